// Round 2
// baseline (1874.009 us; speedup 1.0000x reference)
//
#include <hip/hip_runtime.h>

// GCN critic: 4 layers (128->16->16->16->1), symmetric gcn_norm with self-loops,
// global mean pool. N=100000 nodes, E=6400000 edges.

#define BLK 256

static __device__ __forceinline__ float relu_(float v) { return v > 0.f ? v : 0.f; }

// ---- init: deg = 1.0 (self-loop weight), zero d_out ----
__global__ __launch_bounds__(BLK) void k_init(float* __restrict__ deg, float* __restrict__ out, int n) {
    int i = blockIdx.x * BLK + threadIdx.x;
    if (i < n) deg[i] = 1.0f;
    if (i == 0) out[0] = 0.0f;
}

// ---- degree accumulation: deg[dst[e]] += w[e] ----
__global__ __launch_bounds__(BLK) void k_deg(const int* __restrict__ dst, const float* __restrict__ w,
                                             float* __restrict__ deg, int E) {
    int e = blockIdx.x * BLK + threadIdx.x;
    if (e < E) atomicAdd(&deg[dst[e]], w[e]);
}

// ---- dis = 1/sqrt(deg)  (in place) ----
__global__ __launch_bounds__(BLK) void k_dis(float* __restrict__ d, int n) {
    int i = blockIdx.x * BLK + threadIdx.x;
    if (i < n) {
        float v = d[i];
        d[i] = (v > 0.f) ? (float)(1.0 / sqrt((double)v)) : 0.f;
    }
}

// ---- norm[e] = dis[src]*w*dis[dst] ----
__global__ __launch_bounds__(BLK) void k_norm(const int* __restrict__ src, const int* __restrict__ dst,
                                              const float* __restrict__ w, const float* __restrict__ dis,
                                              float* __restrict__ norm, int E) {
    int e = blockIdx.x * BLK + threadIdx.x;
    if (e < E) norm[e] = dis[src[e]] * w[e] * dis[dst[e]];
}

// ---- dense: z = act(xin) @ W ; acc = z * dis^2 (self-loop init) ----
// act = relu(x + bprev) if RELU else identity. One thread per (node, out-feature).
template<int FI, int FO, bool RELU>
__global__ __launch_bounds__(BLK) void k_dense(const float* __restrict__ xin, const float* __restrict__ W,
                                               const float* __restrict__ bprev, const float* __restrict__ dis,
                                               float* __restrict__ z, float* __restrict__ acc, int n) {
    constexpr int NPB = BLK / FO;          // nodes per block
    constexpr int XP = FI + 1;             // padded pitch, breaks bank aliasing
    __shared__ float Wl[FI * FO];
    __shared__ float xs[NPB * XP];
    const int t = threadIdx.x;
    for (int i = t; i < FI * FO; i += BLK) Wl[i] = W[i];
    const int node0 = blockIdx.x * NPB;
    // stage input rows (coalesced), fusing previous layer's bias+relu
    for (int i = t; i < NPB * FI; i += BLK) {
        int r = i / FI, c = i - r * FI;
        int node = node0 + r;
        float v = 0.f;
        if (node < n) {
            v = xin[node * FI + c];
            if constexpr (RELU) v = relu_(v + bprev[c]);
        }
        xs[r * XP + c] = v;
    }
    __syncthreads();
    const int r = t / FO, j = t - r * FO;
    const int node = node0 + r;
    if (node < n) {
        float s = 0.f;
#pragma unroll
        for (int k = 0; k < FI; ++k) s += xs[r * XP + k] * Wl[k * FO + j];
        z[node * FO + j] = s;
        float di = dis[node];
        acc[node * FO + j] = s * di * di;   // self-loop: norm = dis^2 = 1/deg
    }
}

// ---- scatter: acc[dst*FO+j] += z[src*FO+j] * norm[e] ; FO lanes per edge ----
template<int FO>
__global__ __launch_bounds__(BLK) void k_scatter(const int* __restrict__ src, const int* __restrict__ dst,
                                                 const float* __restrict__ norm, const float* __restrict__ z,
                                                 float* __restrict__ acc, int E) {
    long long tid = (long long)blockIdx.x * BLK + threadIdx.x;
    int e = (int)(tid / FO);
    int j = (int)(tid - (long long)e * FO);
    if (e < E) {
        int s = src[e], d = dst[e];
        float v = z[s * FO + j] * norm[e];
        atomicAdd(&acc[d * FO + j], v);
    }
}

// ---- final: out[0] = mean(relu(acc + b4)) ----
__global__ __launch_bounds__(BLK) void k_reduce(const float* __restrict__ acc, const float* __restrict__ b4,
                                                float* __restrict__ out, int n) {
    int i = blockIdx.x * BLK + threadIdx.x;
    float v = 0.f;
    if (i < n) v = relu_(acc[i] + b4[0]);
#pragma unroll
    for (int off = 32; off > 0; off >>= 1) v += __shfl_down(v, off, 64);
    __shared__ float wsum[BLK / 64];
    int lane = threadIdx.x & 63, wid = threadIdx.x >> 6;
    if (lane == 0) wsum[wid] = v;
    __syncthreads();
    if (threadIdx.x == 0) {
        float s = 0.f;
#pragma unroll
        for (int k = 0; k < BLK / 64; ++k) s += wsum[k];
        atomicAdd(out, s / (float)n);
    }
}

static inline size_t align_up(size_t x) { return (x + 255) & ~(size_t)255; }

extern "C" void kernel_launch(void* const* d_in, const int* in_sizes, int n_in,
                              void* d_out, int out_size, void* d_ws, size_t ws_size,
                              hipStream_t stream) {
    const float* vf  = (const float*)d_in[0];   // [N,128]
    const int*   edg = (const int*)d_in[1];     // [2,E] int32
    const float* w   = (const float*)d_in[2];   // [E]
    const float* W1  = (const float*)d_in[3];
    const float* b1  = (const float*)d_in[4];
    const float* W2  = (const float*)d_in[5];
    const float* b2  = (const float*)d_in[6];
    const float* W3  = (const float*)d_in[7];
    const float* b3  = (const float*)d_in[8];
    const float* W4  = (const float*)d_in[9];
    const float* b4  = (const float*)d_in[10];
    float* out = (float*)d_out;

    const int n = in_sizes[0] / 128;   // 100000
    const int E = in_sizes[2];         // 6400000
    const int* src = edg;
    const int* dst = edg + E;

    char* ws = (char*)d_ws;
    size_t off = 0;
    float* dis  = (float*)(ws + off); off += align_up((size_t)n * 4);
    float* norm = (float*)(ws + off); off += align_up((size_t)E * 4);
    float* z    = (float*)(ws + off); off += align_up((size_t)n * 16 * 4);
    float* accA = (float*)(ws + off); off += align_up((size_t)n * 16 * 4);
    float* accB = (float*)(ws + off); off += align_up((size_t)n * 16 * 4);
    (void)ws_size;

    const int gN  = (n + BLK - 1) / BLK;
    const int gE  = (E + BLK - 1) / BLK;
    const int gD16 = (n + (BLK / 16) - 1) / (BLK / 16);   // dense FO=16: 16 nodes/block
    const int gS16 = (int)(((long long)E * 16 + BLK - 1) / BLK);

    k_init<<<gN, BLK, 0, stream>>>(dis, out, n);
    k_deg<<<gE, BLK, 0, stream>>>(dst, w, dis, E);
    k_dis<<<gN, BLK, 0, stream>>>(dis, n);
    k_norm<<<gE, BLK, 0, stream>>>(src, dst, w, dis, norm, E);

    // layer 1: 128 -> 16
    k_dense<128, 16, false><<<gD16, BLK, 0, stream>>>(vf, W1, nullptr, dis, z, accA, n);
    k_scatter<16><<<gS16, BLK, 0, stream>>>(src, dst, norm, z, accA, E);
    // layer 2: 16 -> 16
    k_dense<16, 16, true><<<gD16, BLK, 0, stream>>>(accA, W2, b1, dis, z, accB, n);
    k_scatter<16><<<gS16, BLK, 0, stream>>>(src, dst, norm, z, accB, E);
    // layer 3: 16 -> 16
    k_dense<16, 16, true><<<gD16, BLK, 0, stream>>>(accB, W3, b2, dis, z, accA, n);
    k_scatter<16><<<gS16, BLK, 0, stream>>>(src, dst, norm, z, accA, E);
    // layer 4: 16 -> 1
    k_dense<16, 1, true><<<gN, BLK, 0, stream>>>(accA, W4, b3, dis, z, accB, n);
    k_scatter<1><<<gE, BLK, 0, stream>>>(src, dst, norm, z, accB, E);

    k_reduce<<<gN, BLK, 0, stream>>>(accB, b4, out, n);
}

// Round 3
// 1600.031 us; speedup vs baseline: 1.1712x; 1.1712x over previous
//
#include <hip/hip_runtime.h>

// GCN critic: 4 layers (128->16->16->16->1), symmetric gcn_norm with self-loops,
// global mean pool. N=100000 nodes, E=6400000 edges.
// R2: CSR-by-dst (counting sort per call) + atomic-free gather aggregation.

#define BLK 256

static __device__ __forceinline__ float relu_(float v) { return v > 0.f ? v : 0.f; }

// ---- init: deg = 1.0 (self-loop weight), cnt = 0, zero d_out ----
__global__ __launch_bounds__(BLK) void k_init(float* __restrict__ deg, int* __restrict__ cnt,
                                              float* __restrict__ out, int n) {
    int i = blockIdx.x * BLK + threadIdx.x;
    if (i < n) { deg[i] = 1.0f; cnt[i] = 0; }
    if (i == 0) out[0] = 0.0f;
}

// ---- degree + histogram: deg[dst] += w ; cnt[dst]++ ----
__global__ __launch_bounds__(BLK) void k_deg_hist(const int* __restrict__ dst, const float* __restrict__ w,
                                                  float* __restrict__ deg, int* __restrict__ cnt, int E) {
    int e = blockIdx.x * BLK + threadIdx.x;
    if (e < E) {
        int d = dst[e];
        atomicAdd(&deg[d], w[e]);
        atomicAdd(&cnt[d], 1);
    }
}

// ---- dis = 1/sqrt(deg)  (in place) ----
__global__ __launch_bounds__(BLK) void k_dis(float* __restrict__ d, int n) {
    int i = blockIdx.x * BLK + threadIdx.x;
    if (i < n) {
        float v = d[i];
        d[i] = (v > 0.f) ? (float)(1.0 / sqrt((double)v)) : 0.f;
    }
}

// ---- two-level exclusive scan of cnt -> rowptr ----
// scan1: per-block (1024 elems = 256 threads x 4) exclusive scan + block total
__global__ __launch_bounds__(BLK) void k_scan1(const int* __restrict__ cnt, int* __restrict__ rowptr,
                                               int* __restrict__ bsum, int n) {
    __shared__ int sc[BLK];
    int t = threadIdx.x;
    int base = blockIdx.x * (BLK * 4) + t * 4;
    int v0 = 0, v1 = 0, v2 = 0, v3 = 0;
    if (base + 0 < n) v0 = cnt[base + 0];
    if (base + 1 < n) v1 = cnt[base + 1];
    if (base + 2 < n) v2 = cnt[base + 2];
    if (base + 3 < n) v3 = cnt[base + 3];
    int tot = v0 + v1 + v2 + v3;
    sc[t] = tot;
    __syncthreads();
    for (int o = 1; o < BLK; o <<= 1) {
        int x = 0;
        if (t >= o) x = sc[t - o];
        __syncthreads();
        sc[t] += x;
        __syncthreads();
    }
    int inc = sc[t];
    int exc = inc - tot;
    if (base + 0 < n) rowptr[base + 0] = exc;
    if (base + 1 < n) rowptr[base + 1] = exc + v0;
    if (base + 2 < n) rowptr[base + 2] = exc + v0 + v1;
    if (base + 3 < n) rowptr[base + 3] = exc + v0 + v1 + v2;
    if (t == BLK - 1) bsum[blockIdx.x] = inc;
}

// scan2: single block, exclusive scan of block sums (nb <= 256)
__global__ __launch_bounds__(BLK) void k_scan2(int* __restrict__ bsum, int nb) {
    __shared__ int sc[BLK];
    int t = threadIdx.x;
    int v = (t < nb) ? bsum[t] : 0;
    sc[t] = v;
    __syncthreads();
    for (int o = 1; o < BLK; o <<= 1) {
        int x = 0;
        if (t >= o) x = sc[t - o];
        __syncthreads();
        sc[t] += x;
        __syncthreads();
    }
    if (t < nb) bsum[t] = sc[t] - v;
}

// scan3: add block offsets; fillpos = rowptr copy for the fill kernel's cursors
__global__ __launch_bounds__(BLK) void k_scan3(int* __restrict__ rowptr, const int* __restrict__ bsum,
                                               int* __restrict__ fillpos, int n) {
    int i = blockIdx.x * BLK + threadIdx.x;
    if (i < n) {
        int r = rowptr[i] + bsum[i >> 10];
        rowptr[i] = r;
        fillpos[i] = r;
    }
}

// ---- fill CSR: ep[p] = {src, norm} where norm = dis[src]*w*dis[dst] ----
__global__ __launch_bounds__(BLK) void k_fill(const int* __restrict__ src, const int* __restrict__ dst,
                                              const float* __restrict__ w, const float* __restrict__ dis,
                                              int* __restrict__ fillpos, int2* __restrict__ ep, int E) {
    int e = blockIdx.x * BLK + threadIdx.x;
    if (e < E) {
        int s = src[e], d = dst[e];
        int p = atomicAdd(&fillpos[d], 1);
        int2 pr;
        pr.x = s;
        pr.y = __float_as_int(dis[s] * w[e] * dis[d]);
        ep[p] = pr;
    }
}

// ---- dense: z = act(xin) @ W ; act = relu(x + bprev) if RELU ----
template<int FI, int FO, bool RELU>
__global__ __launch_bounds__(BLK) void k_dense(const float* __restrict__ xin, const float* __restrict__ W,
                                               const float* __restrict__ bprev, float* __restrict__ z, int n) {
    constexpr int NPB = BLK / FO;          // nodes per block
    constexpr int XP = FI + 1;             // padded pitch
    __shared__ float Wl[FI * FO];
    __shared__ float xs[NPB * XP];
    const int t = threadIdx.x;
    for (int i = t; i < FI * FO; i += BLK) Wl[i] = W[i];
    const int node0 = blockIdx.x * NPB;
    for (int i = t; i < NPB * FI; i += BLK) {
        int r = i / FI, c = i - r * FI;
        int node = node0 + r;
        float v = 0.f;
        if (node < n) {
            v = xin[node * FI + c];
            if constexpr (RELU) v = relu_(v + bprev[c]);
        }
        xs[r * XP + c] = v;
    }
    __syncthreads();
    const int r = t / FO, j = t - r * FO;
    const int node = node0 + r;
    if (node < n) {
        float s = 0.f;
#pragma unroll
        for (int k = 0; k < FI; ++k) s += xs[r * XP + k] * Wl[k * FO + j];
        z[node * FO + j] = s;
    }
}

// ---- gather (FO=16): one wave per node. lane = (g=lane>>4 edge subgroup, j=lane&15 feature)
// acc[i*16+j] = z[i*16+j]*dis^2 + sum_e z[col[e]*16+j]*val[e]
__global__ __launch_bounds__(BLK) void k_gather16(const int2* __restrict__ ep, const int* __restrict__ rowptr,
                                                  const int* __restrict__ cnt, const float* __restrict__ dis,
                                                  const float* __restrict__ z, float* __restrict__ acc, int n) {
    int wv = (blockIdx.x * BLK + threadIdx.x) >> 6;  // node id
    int lane = threadIdx.x & 63;
    if (wv >= n) return;
    int j = lane & 15, g = lane >> 4;
    int start = rowptr[wv], len = cnt[wv];
    float s = 0.f;
    for (int e = start + g; e < start + len; e += 4) {
        int2 pr = ep[e];
        s += z[pr.x * 16 + j] * __int_as_float(pr.y);
    }
    s += __shfl_xor(s, 16, 64);
    s += __shfl_xor(s, 32, 64);
    if (g == 0) {
        float di = dis[wv];
        acc[wv * 16 + j] = z[wv * 16 + j] * di * di + s;
    }
}

// ---- gather (FO=1): one wave per node, 64 edges/step ----
__global__ __launch_bounds__(BLK) void k_gather1(const int2* __restrict__ ep, const int* __restrict__ rowptr,
                                                 const int* __restrict__ cnt, const float* __restrict__ dis,
                                                 const float* __restrict__ z1, float* __restrict__ acc1, int n) {
    int wv = (blockIdx.x * BLK + threadIdx.x) >> 6;
    int lane = threadIdx.x & 63;
    if (wv >= n) return;
    int start = rowptr[wv], len = cnt[wv];
    float s = 0.f;
    for (int e = start + lane; e < start + len; e += 64) {
        int2 pr = ep[e];
        s += z1[pr.x] * __int_as_float(pr.y);
    }
#pragma unroll
    for (int o = 32; o > 0; o >>= 1) s += __shfl_xor(s, o, 64);
    if (lane == 0) {
        float di = dis[wv];
        acc1[wv] = z1[wv] * di * di + s;
    }
}

// ---- final: out[0] = mean(relu(acc1 + b4)) ----
__global__ __launch_bounds__(BLK) void k_reduce(const float* __restrict__ acc, const float* __restrict__ b4,
                                                float* __restrict__ out, int n) {
    int i = blockIdx.x * BLK + threadIdx.x;
    float v = 0.f;
    if (i < n) v = relu_(acc[i] + b4[0]);
#pragma unroll
    for (int off = 32; off > 0; off >>= 1) v += __shfl_down(v, off, 64);
    __shared__ float wsum[BLK / 64];
    int lane = threadIdx.x & 63, wid = threadIdx.x >> 6;
    if (lane == 0) wsum[wid] = v;
    __syncthreads();
    if (threadIdx.x == 0) {
        float s = 0.f;
#pragma unroll
        for (int k = 0; k < BLK / 64; ++k) s += wsum[k];
        atomicAdd(out, s / (float)n);
    }
}

static inline size_t align_up(size_t x) { return (x + 255) & ~(size_t)255; }

extern "C" void kernel_launch(void* const* d_in, const int* in_sizes, int n_in,
                              void* d_out, int out_size, void* d_ws, size_t ws_size,
                              hipStream_t stream) {
    const float* vf  = (const float*)d_in[0];   // [N,128]
    const int*   edg = (const int*)d_in[1];     // [2,E] int32
    const float* w   = (const float*)d_in[2];   // [E]
    const float* W1  = (const float*)d_in[3];
    const float* b1  = (const float*)d_in[4];
    const float* W2  = (const float*)d_in[5];
    const float* b2  = (const float*)d_in[6];
    const float* W3  = (const float*)d_in[7];
    const float* b3  = (const float*)d_in[8];
    const float* W4  = (const float*)d_in[9];
    const float* b4  = (const float*)d_in[10];
    float* out = (float*)d_out;

    const int n = in_sizes[0] / 128;   // 100000
    const int E = in_sizes[2];         // 6400000
    const int* src = edg;
    const int* dst = edg + E;

    char* ws = (char*)d_ws;
    size_t off = 0;
    float* dis     = (float*)(ws + off); off += align_up((size_t)n * 4);
    int*   cnt     = (int*)(ws + off);   off += align_up((size_t)n * 4);
    int*   rowptr  = (int*)(ws + off);   off += align_up((size_t)n * 4);
    int*   fillpos = (int*)(ws + off);   off += align_up((size_t)n * 4);
    int*   bsum    = (int*)(ws + off);   off += align_up((size_t)256 * 4);
    int2*  ep      = (int2*)(ws + off);  off += align_up((size_t)E * 8);
    float* z       = (float*)(ws + off); off += align_up((size_t)n * 16 * 4);
    float* acc     = (float*)(ws + off); off += align_up((size_t)n * 16 * 4);
    float* z1   = z;    // layer-4 (FO=1) aliases: only n floats used
    float* acc1 = acc;
    (void)ws_size;

    const int gN = (n + BLK - 1) / BLK;
    const int gE = (E + BLK - 1) / BLK;
    const int gD16 = (n + (BLK / 16) - 1) / (BLK / 16);  // dense FO=16: 16 nodes/block
    const int gW = (n + 3) / 4;                          // wave-per-node kernels
    const int nb = (n + BLK * 4 - 1) / (BLK * 4);        // scan blocks (98)

    k_init<<<gN, BLK, 0, stream>>>(dis, cnt, out, n);
    k_deg_hist<<<gE, BLK, 0, stream>>>(dst, w, dis, cnt, E);
    k_dis<<<gN, BLK, 0, stream>>>(dis, n);
    k_scan1<<<nb, BLK, 0, stream>>>(cnt, rowptr, bsum, n);
    k_scan2<<<1, BLK, 0, stream>>>(bsum, nb);
    k_scan3<<<gN, BLK, 0, stream>>>(rowptr, bsum, fillpos, n);
    k_fill<<<gE, BLK, 0, stream>>>(src, dst, w, dis, fillpos, ep, E);

    // layer 1: 128 -> 16
    k_dense<128, 16, false><<<gD16, BLK, 0, stream>>>(vf, W1, nullptr, z, n);
    k_gather16<<<gW, BLK, 0, stream>>>(ep, rowptr, cnt, dis, z, acc, n);
    // layer 2: 16 -> 16
    k_dense<16, 16, true><<<gD16, BLK, 0, stream>>>(acc, W2, b1, z, n);
    k_gather16<<<gW, BLK, 0, stream>>>(ep, rowptr, cnt, dis, z, acc, n);
    // layer 3: 16 -> 16
    k_dense<16, 16, true><<<gD16, BLK, 0, stream>>>(acc, W3, b2, z, n);
    k_gather16<<<gW, BLK, 0, stream>>>(ep, rowptr, cnt, dis, z, acc, n);
    // layer 4: 16 -> 1
    k_dense<16, 1, true><<<gN, BLK, 0, stream>>>(acc, W4, b3, z1, n);
    k_gather1<<<gW, BLK, 0, stream>>>(ep, rowptr, cnt, dis, z1, acc1, n);

    k_reduce<<<gN, BLK, 0, stream>>>(acc1, b4, out, n);
}